// Round 3
// baseline (203.069 us; speedup 1.0000x reference)
//
#include <hip/hip_runtime.h>
#include <stdint.h>

#define DIMC  128
#define HEADS 8
#define HD    16
#define WIN   512
#define LTOT  32768
#define NB    2

typedef __bf16 bf16x8_t __attribute__((ext_vector_type(8)));
typedef float f32x16_t  __attribute__((ext_vector_type(16)));
typedef float f32x4_t   __attribute__((ext_vector_type(4)));
typedef unsigned int u32x2_t __attribute__((ext_vector_type(2)));
union U128 { uint4 u; bf16x8_t v; };

__device__ __forceinline__ uint32_t rne_pair(float lo, float hi) {
    uint32_t a = __float_as_uint(lo), b = __float_as_uint(hi);
    a = (a + 0x7fffu + ((a >> 16) & 1u)) >> 16;
    b = (b + 0x7fffu + ((b >> 16) & 1u)) >> 16;
    return a | (b << 16);
}
__device__ __forceinline__ unsigned short rne1(float x) {
    uint32_t a = __float_as_uint(x);
    return (unsigned short)((a + 0x7fffu + ((a >> 16) & 1u)) >> 16);
}
// (lo>>16) | (hi & 0xffff0000): single v_perm_b32, bit-identical RTZ pack.
__device__ __forceinline__ uint32_t trunc_pair(float lo, float hi) {
    return __builtin_amdgcn_perm(__float_as_uint(hi), __float_as_uint(lo), 0x07060302u);
}
__device__ __forceinline__ float fast_exp2(float x) {
#if __has_builtin(__builtin_amdgcn_exp2f)
    return __builtin_amdgcn_exp2f(x);
#else
    return exp2f(x);
#endif
}

// One block per (window, head), 8 waves x 64 q-rows each (512 threads).
// Halved per-wave tile vs prior rev: acc 64->32 VGPR, qf 16->8, so the
// whole wave fits ~85 regs -> 6 waves/SIMD (3 blocks/CU, LDS 3x38.4KB).
// 32x32x16 MFMA for S^T = K*Q^T and O = P*V. P transposed C->A in-register
// via v_permlane32_swap_b32 (swap(pk0,pk2): r0=A0.x, r1=A0.z). Softmax
// without max-subtraction, den via ones-row in Vt. LePE depthwise conv as
// per-channel im2col MFMA (16x16x32), 2 channels per wave.
__global__ void __launch_bounds__(512, 6) attn_lepe(
    const float* __restrict__ qkv,   // [3, 2, 32768, 128] fp32
    const float* __restrict__ wgt,   // [128, 1, 5, 5, 5]  fp32
    const float* __restrict__ bias,  // [128]              fp32
    float* __restrict__ out)         // [2, 32768, 128]    fp32
{
    // Kf: K A-fragments (16 chunks x 512 bf16). Reused as conv-out Cl[token][ch].
    __shared__ __align__(16) unsigned short Kf[16 * 512];      // 16384 B
    // Vt: channel-major V, rows 0..15 = channels, row 16 = ones (den). Padded 520.
    __shared__ __align__(16) unsigned short Vt[17 * 520];      // 17680 B
    __shared__ __align__(16) unsigned short Wb[125 * 16];      // 4000 B, [tap][ch]
    __shared__ __align__(16) unsigned short Zp[16];            // 32 B zeros (conv halo)

    const int blk  = blockIdx.x;
    const int head = blk >> 7;          // swizzle: 8 heads of a window adjacent
    const int wi   = blk & 127;
    const int b    = wi >> 6;
    const int rem  = wi & 63;
    const int lbase = ((rem >> 3) << 7) + ((rem & 7) << 2);
    const int t    = threadIdx.x;
    const int lane = t & 63;
    const int wv   = t >> 6;            // 0..7
    const int cbase = head * HD;

    const int col  = lane & 31;
    const int hsel = lane >> 5;

    const float* Qg = qkv + (size_t)b * LTOT * DIMC;
    const float* Kg = Qg + (size_t)NB * LTOT * DIMC;
    const float* Vg = Kg + (size_t)NB * LTOT * DIMC;

    // ---------- stage K (A-frag order) and V (channel-major) ----------
    for (int u = t; u < 1024; u += 512) {
        int tp = u >> 2, ch4 = u & 3;
        int p  = tp << 1;               // even token; p+1 is l+1 (same h,w)
        int hh = p >> 4, ww = (p >> 2) & 3, ss = p & 3;
        int l  = (hh << 10) + lbase + (ww << 5) + ss;
        size_t g = (size_t)l * DIMC + cbase + (ch4 << 2);
        float4 k0 = *(const float4*)&Kg[g];
        float4 k1 = *(const float4*)&Kg[g + DIMC];
        float4 v0 = *(const float4*)&Vg[g];
        float4 v1 = *(const float4*)&Vg[g + DIMC];
        // Kf: value(lane,j) = K[c*32 + (lane&31)][8*(lane>>5)+j]
        int c  = p >> 5;
        int fl = (p & 31) + ((ch4 >> 1) << 5);
        int jo = (ch4 & 1) << 2;
        *(uint2*)&Kf[c * 512 + fl * 8 + jo] =
            make_uint2(rne_pair(k0.x, k0.y), rne_pair(k0.z, k0.w));
        *(uint2*)&Kf[c * 512 + (fl + 1) * 8 + jo] =
            make_uint2(rne_pair(k1.x, k1.y), rne_pair(k1.z, k1.w));
        // Vt: pair write (tokens p, p+1) per channel
        float a0[4] = {v0.x, v0.y, v0.z, v0.w};
        float a1[4] = {v1.x, v1.y, v1.z, v1.w};
#pragma unroll
        for (int i = 0; i < 4; ++i)
            *(uint32_t*)&Vt[((ch4 << 2) + i) * 520 + p] = rne_pair(a0[i], a1[i]);
    }
    // ones row (den): 512 entries = 128 threads x 4 bf16
    if (t < 128) ((uint2*)&Vt[16 * 520])[t] = make_uint2(0x3F803F80u, 0x3F803F80u);
    if (t < 8)  ((uint32_t*)Zp)[t & 7] = 0u;
    for (int e = t; e < 125 * HD; e += 512) {
        int tap = e >> 4, d = e & 15;
        Wb[e] = rne1(wgt[(size_t)(cbase + d) * 125 + tap]);
    }

    // ---------- per-wave Q B-fragments (scale * log2(e) folded in) ----------
    const float QSC = 0.25f * 1.44269504088896340736f;
    bf16x8_t qf[2];
#pragma unroll
    for (int mt = 0; mt < 2; ++mt) {
        int qrow = wv * 64 + mt * 32 + col;
        int l = ((qrow >> 4) << 10) + lbase + (((qrow >> 2) & 3) << 5) + (qrow & 3);
        const float* qp = &Qg[(size_t)l * DIMC + cbase + hsel * 8];
        float4 a = *(const float4*)qp;
        float4 c4 = *(const float4*)(qp + 4);
        U128 u;
        u.u.x = rne_pair(a.x * QSC, a.y * QSC);
        u.u.y = rne_pair(a.z * QSC, a.w * QSC);
        u.u.z = rne_pair(c4.x * QSC, c4.y * QSC);
        u.u.w = rne_pair(c4.z * QSC, c4.w * QSC);
        qf[mt] = u.v;
    }
    float breg = (col < HD) ? bias[cbase + col] : 0.f;

    __syncthreads();

    // ---------- attention main loop ----------
    f32x16_t acc[2];
#pragma unroll
    for (int mt = 0; mt < 2; ++mt)
#pragma unroll
        for (int i = 0; i < 16; ++i) acc[mt][i] = 0.f;
    f32x16_t zv;
#pragma unroll
    for (int i = 0; i < 16; ++i) zv[i] = 0.f;

    const int vcol = (col <= 16) ? col : 16;
    const int voff = vcol * 520;

    for (int c = 0; c < 16; ++c) {
        U128 kf;  kf.u  = *(const uint4*)&Kf[c * 512 + lane * 8];
        U128 vf0; vf0.u = *(const uint4*)&Vt[voff + c * 32 + hsel * 8];
        U128 vf1; vf1.u = *(const uint4*)&Vt[voff + c * 32 + 16 + hsel * 8];
#pragma unroll
        for (int mt = 0; mt < 2; ++mt) {
            f32x16_t S = __builtin_amdgcn_mfma_f32_32x32x16_bf16(kf.v, qf[mt], zv, 0, 0, 0);
            // pe packed pairs: pk[r] = (pe[2r], pe[2r+1]); reg i -> key (i&3)+8*(i>>2)+4*hsel
            uint32_t pk[8];
#pragma unroll
            for (int r = 0; r < 8; ++r)
                pk[r] = trunc_pair(fast_exp2(S[2 * r]), fast_exp2(S[2 * r + 1]));
            // C->A half-transpose: permlane32_swap(vdst=pk0, vsrc=pk2):
            //   r[0] = {pk0.lanes0-31, pk2.lanes0-31} = A0.x
            //   r[1] = {pk0.lanes32-63, pk2.lanes32-63} = A0.z
            U128 A0, A1;
#if __has_builtin(__builtin_amdgcn_permlane32_swap)
            u32x2_t rxz0 = __builtin_amdgcn_permlane32_swap(pk[0], pk[2], false, false);
            u32x2_t ryw0 = __builtin_amdgcn_permlane32_swap(pk[1], pk[3], false, false);
            u32x2_t rxz1 = __builtin_amdgcn_permlane32_swap(pk[4], pk[6], false, false);
            u32x2_t ryw1 = __builtin_amdgcn_permlane32_swap(pk[5], pk[7], false, false);
            A0.u = make_uint4(rxz0[0], ryw0[0], rxz0[1], ryw0[1]);
            A1.u = make_uint4(rxz1[0], ryw1[0], rxz1[1], ryw1[1]);
#else
            uint32_t xa = __shfl_xor(hsel ? pk[0] : pk[2], 32);
            uint32_t xb = __shfl_xor(hsel ? pk[1] : pk[3], 32);
            uint32_t xc = __shfl_xor(hsel ? pk[4] : pk[6], 32);
            uint32_t xd = __shfl_xor(hsel ? pk[5] : pk[7], 32);
            A0.u = hsel ? make_uint4(xa, xb, pk[2], pk[3])
                        : make_uint4(pk[0], pk[1], xa, xb);
            A1.u = hsel ? make_uint4(xc, xd, pk[6], pk[7])
                        : make_uint4(pk[4], pk[5], xc, xd);
#endif
            acc[mt] = __builtin_amdgcn_mfma_f32_32x32x16_bf16(A0.v, vf0.v, acc[mt], 0, 0, 0);
            acc[mt] = __builtin_amdgcn_mfma_f32_32x32x16_bf16(A1.v, vf1.v, acc[mt], 0, 0, 0);
        }
    }

    __syncthreads();   // all waves done with Kf -> reuse as Cl

    // ---------- LePE conv as per-channel im2col MFMA ----------
    // C[h][sigma] = sum_{dh,tau} V[h+dh-2][tau][ch] * M[(dh,tau)][sigma]
    {
        const int sg  = lane & 15;       // sigma = w*4+s (output ws)
        const int khi = lane >> 4;       // k-group
        const int tb  = (khi & 1) * 8;   // tau base for this lane's j-run
#pragma unroll
        for (int cc = 0; cc < 2; ++cc) {
            const int cch = wv * 2 + cc;
            // B-frags: Toeplitz weights, built from Wb
            U128 Bf[3];
#pragma unroll
            for (int kc = 0; kc < 3; ++kc) {
                int dh = 2 * kc + (khi >> 1);
                uint32_t pr[4];
#pragma unroll
                for (int jp = 0; jp < 4; ++jp) {
                    uint32_t w01 = 0;
#pragma unroll
                    for (int e = 0; e < 2; ++e) {
                        int tau = tb + jp * 2 + e;
                        int dw = (tau >> 2) - (sg >> 2);
                        int ds = (tau & 3) - (sg & 3);
                        bool valid = (dh < 5) && (dw >= -2) && (dw <= 2) && (ds >= -2) && (ds <= 2);
                        int tap = dh * 25 + (dw + 2) * 5 + (ds + 2);
                        uint32_t wv16 = valid ? (uint32_t)Wb[(valid ? tap : 0) * 16 + cch] : 0u;
                        w01 |= wv16 << (16 * e);
                    }
                    pr[jp] = w01;
                }
                Bf[kc].u = make_uint4(pr[0], pr[1], pr[2], pr[3]);
            }
#pragma unroll
            for (int mt2 = 0; mt2 < 2; ++mt2) {
                f32x4_t cacc = {0.f, 0.f, 0.f, 0.f};
#pragma unroll
                for (int kc = 0; kc < 3; ++kc) {
                    int dh = 2 * kc + (khi >> 1);
                    int h_in = mt2 * 16 + (lane & 15) + dh - 2;
                    const unsigned short* ap =
                        (h_in >= 0 && h_in < 32 && dh < 5)
                            ? &Vt[cch * 520 + h_in * 16 + tb]
                            : Zp;
                    U128 af; af.u = *(const uint4*)ap;
                    cacc = __builtin_amdgcn_mfma_f32_16x16x32_bf16(af.v, Bf[kc].v, cacc, 0, 0, 0);
                }
                // C-layout 16x16: col=lane&15 (=sigma), row=(lane>>4)*4+reg
#pragma unroll
                for (int r = 0; r < 4; ++r) {
                    int h = mt2 * 16 + khi * 4 + r;
                    Kf[(h * 16 + sg) * 16 + cch] = rne1(cacc[r]);
                }
            }
        }
    }

    __syncthreads();

    // ---------- epilogue: O/den + bias + conv ----------
    const int ccol = col & 15;
#pragma unroll
    for (int mt = 0; mt < 2; ++mt) {
#pragma unroll
        for (int i = 0; i < 16; ++i) {
            float dv = __shfl(acc[mt][i], 16 | (lane & 32), 64);  // den col 16
            int row = (i & 3) + ((i >> 2) << 3) + (hsel << 2);
            int token = wv * 64 + mt * 32 + row;
            float cvv = __uint_as_float(((uint32_t)Kf[token * 16 + ccol]) << 16);
            float oval = acc[mt][i] * __builtin_amdgcn_rcpf(dv) + breg + cvv;
            if (col < HD) {
                int l = ((token >> 4) << 10) + lbase + (((token >> 2) & 3) << 5) + (token & 3);
                out[((size_t)b * LTOT + l) * DIMC + cbase + col] = oval;
            }
        }
    }
}

extern "C" void kernel_launch(void* const* d_in, const int* in_sizes, int n_in,
                              void* d_out, int out_size, void* d_ws, size_t ws_size,
                              hipStream_t stream) {
    const float* qkv  = (const float*)d_in[0];
    const float* wgt  = (const float*)d_in[1];
    const float* bias = (const float*)d_in[2];
    float* out = (float*)d_out;
    attn_lepe<<<dim3(1024), dim3(512), 0, stream>>>(qkv, wgt, bias, out);
}

// Round 5
// 194.405 us; speedup vs baseline: 1.0446x; 1.0446x over previous
//
#include <hip/hip_runtime.h>
#include <stdint.h>

#define DIMC  128
#define HEADS 8
#define HD    16
#define WIN   512
#define LTOT  32768
#define NB    2

typedef __bf16 bf16x8_t __attribute__((ext_vector_type(8)));
typedef float f32x16_t  __attribute__((ext_vector_type(16)));
typedef float f32x4_t   __attribute__((ext_vector_type(4)));
typedef unsigned int u32x2_t __attribute__((ext_vector_type(2)));
union U128 { uint4 u; bf16x8_t v; };

__device__ __forceinline__ uint32_t rne_pair(float lo, float hi) {
    uint32_t a = __float_as_uint(lo), b = __float_as_uint(hi);
    a = (a + 0x7fffu + ((a >> 16) & 1u)) >> 16;
    b = (b + 0x7fffu + ((b >> 16) & 1u)) >> 16;
    return a | (b << 16);
}
__device__ __forceinline__ unsigned short rne1(float x) {
    uint32_t a = __float_as_uint(x);
    return (unsigned short)((a + 0x7fffu + ((a >> 16) & 1u)) >> 16);
}
// (lo>>16) | (hi & 0xffff0000): single v_perm_b32, bit-identical RTZ pack.
__device__ __forceinline__ uint32_t trunc_pair(float lo, float hi) {
    return __builtin_amdgcn_perm(__float_as_uint(hi), __float_as_uint(lo), 0x07060302u);
}
__device__ __forceinline__ float fast_exp2(float x) {
#if __has_builtin(__builtin_amdgcn_exp2f)
    return __builtin_amdgcn_exp2f(x);
#else
    return exp2f(x);
#endif
}

// One block per (window, head), 4 waves x 128 q-rows (256 threads), 4 blocks/CU
// (full grid residency -> head-pair L2 write-combining, WRITE_SIZE = output).
// launch_bounds(256,3): registers are the cheap resource (occupancy proven
// irrelevant R2 vs R3); give the compiler headroom to keep the mt-chains and
// exp batch fully live in VGPRs instead of serializing at the 128-reg cliff.
// Main loop: register double-buffer prefetch of next-c LDS fragments takes the
// ~120cy ds_read latency off the chain head. 32x32x16 MFMA for S^T = K*Q^T and
// O = P*V; P transposed C->A in-register via v_permlane32_swap_b32. Softmax
// without max-subtraction, den via ones-row in Vt. LePE conv as per-channel
// im2col MFMA (16x16x32). LDS ~38KB -> 4 blocks/CU.
__global__ void __launch_bounds__(256, 3) attn_lepe(
    const float* __restrict__ qkv,   // [3, 2, 32768, 128] fp32
    const float* __restrict__ wgt,   // [128, 1, 5, 5, 5]  fp32
    const float* __restrict__ bias,  // [128]              fp32
    float* __restrict__ out)         // [2, 32768, 128]    fp32
{
    // Kf: K A-fragments (16 chunks x 512 bf16). Reused as conv-out Cl[token][ch].
    __shared__ __align__(16) unsigned short Kf[16 * 512];      // 16384 B
    // Vt: channel-major V, rows 0..15 = channels, row 16 = ones (den). Padded 520.
    __shared__ __align__(16) unsigned short Vt[17 * 520];      // 17680 B
    __shared__ __align__(16) unsigned short Wb[125 * 16];      // 4000 B, [tap][ch]
    __shared__ __align__(16) unsigned short Zp[16];            // 32 B zeros (conv halo)

    const int blk  = blockIdx.x;
    const int head = blk >> 7;          // swizzle: 8 heads of a window adjacent
    const int wi   = blk & 127;
    const int b    = wi >> 6;
    const int rem  = wi & 63;
    const int lbase = ((rem >> 3) << 7) + ((rem & 7) << 2);
    const int t    = threadIdx.x;
    const int lane = t & 63;
    const int wv   = t >> 6;
    const int cbase = head * HD;

    const int col  = lane & 31;
    const int hsel = lane >> 5;

    const float* Qg = qkv + (size_t)b * LTOT * DIMC;
    const float* Kg = Qg + (size_t)NB * LTOT * DIMC;
    const float* Vg = Kg + (size_t)NB * LTOT * DIMC;

    // ---------- stage K (A-frag order) and V (channel-major) ----------
    for (int u = t; u < 1024; u += 256) {
        int tp = u >> 2, ch4 = u & 3;
        int p  = tp << 1;               // even token; p+1 is l+1 (same h,w)
        int hh = p >> 4, ww = (p >> 2) & 3, ss = p & 3;
        int l  = (hh << 10) + lbase + (ww << 5) + ss;
        size_t g = (size_t)l * DIMC + cbase + (ch4 << 2);
        float4 k0 = *(const float4*)&Kg[g];
        float4 k1 = *(const float4*)&Kg[g + DIMC];
        float4 v0 = *(const float4*)&Vg[g];
        float4 v1 = *(const float4*)&Vg[g + DIMC];
        // Kf: value(lane,j) = K[c*32 + (lane&31)][8*(lane>>5)+j]
        int c  = p >> 5;
        int fl = (p & 31) + ((ch4 >> 1) << 5);
        int jo = (ch4 & 1) << 2;
        *(uint2*)&Kf[c * 512 + fl * 8 + jo] =
            make_uint2(rne_pair(k0.x, k0.y), rne_pair(k0.z, k0.w));
        *(uint2*)&Kf[c * 512 + (fl + 1) * 8 + jo] =
            make_uint2(rne_pair(k1.x, k1.y), rne_pair(k1.z, k1.w));
        // Vt: pair write (tokens p, p+1) per channel
        float a0[4] = {v0.x, v0.y, v0.z, v0.w};
        float a1[4] = {v1.x, v1.y, v1.z, v1.w};
#pragma unroll
        for (int i = 0; i < 4; ++i)
            *(uint32_t*)&Vt[((ch4 << 2) + i) * 520 + p] = rne_pair(a0[i], a1[i]);
    }
    // ones row (den): 512 entries = 128 threads x 4 bf16
    if (t < 128) ((uint2*)&Vt[16 * 520])[t] = make_uint2(0x3F803F80u, 0x3F803F80u);
    if (t < 8)  ((uint32_t*)Zp)[t & 7] = 0u;
    for (int e = t; e < 125 * HD; e += 256) {
        int tap = e >> 4, d = e & 15;
        Wb[e] = rne1(wgt[(size_t)(cbase + d) * 125 + tap]);
    }

    // ---------- per-wave Q B-fragments (scale * log2(e) folded in) ----------
    const float QSC = 0.25f * 1.44269504088896340736f;
    bf16x8_t qf[4];
#pragma unroll
    for (int mt = 0; mt < 4; ++mt) {
        int qrow = wv * 128 + mt * 32 + col;
        int l = ((qrow >> 4) << 10) + lbase + (((qrow >> 2) & 3) << 5) + (qrow & 3);
        const float* qp = &Qg[(size_t)l * DIMC + cbase + hsel * 8];
        float4 a = *(const float4*)qp;
        float4 c4 = *(const float4*)(qp + 4);
        U128 u;
        u.u.x = rne_pair(a.x * QSC, a.y * QSC);
        u.u.y = rne_pair(a.z * QSC, a.w * QSC);
        u.u.z = rne_pair(c4.x * QSC, c4.y * QSC);
        u.u.w = rne_pair(c4.z * QSC, c4.w * QSC);
        qf[mt] = u.v;
    }
    float breg = (col < HD) ? bias[cbase + col] : 0.f;

    __syncthreads();

    // ---------- attention main loop ----------
    f32x16_t acc[4];
#pragma unroll
    for (int mt = 0; mt < 4; ++mt)
#pragma unroll
        for (int i = 0; i < 16; ++i) acc[mt][i] = 0.f;
    f32x16_t zv;
#pragma unroll
    for (int i = 0; i < 16; ++i) zv[i] = 0.f;

    const int vcol = (col <= 16) ? col : 16;
    const int voff = vcol * 520;

    // register double-buffer: LDS fragments for iteration c are loaded at
    // iteration c-1, so the ~120cy ds_read latency overlaps the exp/PV chain.
    U128 kf, vf0, vf1, kfn, vf0n, vf1n;
    kf.u  = *(const uint4*)&Kf[lane * 8];
    vf0.u = *(const uint4*)&Vt[voff + hsel * 8];
    vf1.u = *(const uint4*)&Vt[voff + 16 + hsel * 8];

    for (int c = 0; c < 16; ++c) {
        if (c < 15) {
            kfn.u  = *(const uint4*)&Kf[(c + 1) * 512 + lane * 8];
            vf0n.u = *(const uint4*)&Vt[voff + (c + 1) * 32 + hsel * 8];
            vf1n.u = *(const uint4*)&Vt[voff + (c + 1) * 32 + 16 + hsel * 8];
        }
#pragma unroll
        for (int mt = 0; mt < 4; ++mt) {
            f32x16_t S = __builtin_amdgcn_mfma_f32_32x32x16_bf16(kf.v, qf[mt], zv, 0, 0, 0);
            // pe[r] independent -> batch all 16 exps so they pipeline on the
            // trans unit instead of chaining pairwise.
            float pe[16];
#pragma unroll
            for (int r = 0; r < 16; ++r) pe[r] = fast_exp2(S[r]);
            uint32_t pk[8];
#pragma unroll
            for (int r = 0; r < 8; ++r) pk[r] = trunc_pair(pe[2 * r], pe[2 * r + 1]);
            // C->A half-transpose: permlane32_swap(vdst=pk0, vsrc=pk2):
            //   r[0] = {pk0.lanes0-31, pk2.lanes0-31} = A0.x
            //   r[1] = {pk0.lanes32-63, pk2.lanes32-63} = A0.z
            U128 A0, A1;
#if __has_builtin(__builtin_amdgcn_permlane32_swap)
            u32x2_t rxz0 = __builtin_amdgcn_permlane32_swap(pk[0], pk[2], false, false);
            u32x2_t ryw0 = __builtin_amdgcn_permlane32_swap(pk[1], pk[3], false, false);
            u32x2_t rxz1 = __builtin_amdgcn_permlane32_swap(pk[4], pk[6], false, false);
            u32x2_t ryw1 = __builtin_amdgcn_permlane32_swap(pk[5], pk[7], false, false);
            A0.u = make_uint4(rxz0[0], ryw0[0], rxz0[1], ryw0[1]);
            A1.u = make_uint4(rxz1[0], ryw1[0], rxz1[1], ryw1[1]);
#else
            uint32_t xa = __shfl_xor(hsel ? pk[0] : pk[2], 32);
            uint32_t xb = __shfl_xor(hsel ? pk[1] : pk[3], 32);
            uint32_t xc = __shfl_xor(hsel ? pk[4] : pk[6], 32);
            uint32_t xd = __shfl_xor(hsel ? pk[5] : pk[7], 32);
            A0.u = hsel ? make_uint4(xa, xb, pk[2], pk[3])
                        : make_uint4(pk[0], pk[1], xa, xb);
            A1.u = hsel ? make_uint4(xc, xd, pk[6], pk[7])
                        : make_uint4(pk[4], pk[5], xc, xd);
#endif
            __builtin_amdgcn_s_setprio(1);
            acc[mt] = __builtin_amdgcn_mfma_f32_32x32x16_bf16(A0.v, vf0.v, acc[mt], 0, 0, 0);
            acc[mt] = __builtin_amdgcn_mfma_f32_32x32x16_bf16(A1.v, vf1.v, acc[mt], 0, 0, 0);
            __builtin_amdgcn_s_setprio(0);
        }
        kf = kfn; vf0 = vf0n; vf1 = vf1n;
    }

    __syncthreads();   // all waves done with Kf -> reuse as Cl

    // ---------- LePE conv as per-channel im2col MFMA ----------
    // C[h][sigma] = sum_{dh,tau} V[h+dh-2][tau][ch] * M[(dh,tau)][sigma]
    {
        const int sg  = lane & 15;       // sigma = w*4+s (output ws)
        const int khi = lane >> 4;       // k-group
        const int tb  = (khi & 1) * 8;   // tau base for this lane's j-run
#pragma unroll
        for (int cc = 0; cc < 4; ++cc) {
            const int cch = wv * 4 + cc;
            // B-frags: Toeplitz weights, built from Wb
            U128 Bf[3];
#pragma unroll
            for (int kc = 0; kc < 3; ++kc) {
                int dh = 2 * kc + (khi >> 1);
                uint32_t pr[4];
#pragma unroll
                for (int jp = 0; jp < 4; ++jp) {
                    uint32_t w01 = 0;
#pragma unroll
                    for (int e = 0; e < 2; ++e) {
                        int tau = tb + jp * 2 + e;
                        int dw = (tau >> 2) - (sg >> 2);
                        int ds = (tau & 3) - (sg & 3);
                        bool valid = (dh < 5) && (dw >= -2) && (dw <= 2) && (ds >= -2) && (ds <= 2);
                        int tap = dh * 25 + (dw + 2) * 5 + (ds + 2);
                        uint32_t wv16 = valid ? (uint32_t)Wb[(valid ? tap : 0) * 16 + cch] : 0u;
                        w01 |= wv16 << (16 * e);
                    }
                    pr[jp] = w01;
                }
                Bf[kc].u = make_uint4(pr[0], pr[1], pr[2], pr[3]);
            }
#pragma unroll
            for (int mt2 = 0; mt2 < 2; ++mt2) {
                f32x4_t cacc = {0.f, 0.f, 0.f, 0.f};
#pragma unroll
                for (int kc = 0; kc < 3; ++kc) {
                    int dh = 2 * kc + (khi >> 1);
                    int h_in = mt2 * 16 + (lane & 15) + dh - 2;
                    const unsigned short* ap =
                        (h_in >= 0 && h_in < 32 && dh < 5)
                            ? &Vt[cch * 520 + h_in * 16 + tb]
                            : Zp;
                    U128 af; af.u = *(const uint4*)ap;
                    cacc = __builtin_amdgcn_mfma_f32_16x16x32_bf16(af.v, Bf[kc].v, cacc, 0, 0, 0);
                }
                // C-layout 16x16: col=lane&15 (=sigma), row=(lane>>4)*4+reg
#pragma unroll
                for (int r = 0; r < 4; ++r) {
                    int h = mt2 * 16 + khi * 4 + r;
                    Kf[(h * 16 + sg) * 16 + cch] = rne1(cacc[r]);
                }
            }
        }
    }

    __syncthreads();

    // ---------- epilogue: O/den + bias + conv ----------
    const int ccol = col & 15;
#pragma unroll
    for (int mt = 0; mt < 4; ++mt) {
#pragma unroll
        for (int i = 0; i < 16; ++i) {
            float dv = __shfl(acc[mt][i], 16 | (lane & 32), 64);  // den col 16
            int row = (i & 3) + ((i >> 2) << 3) + (hsel << 2);
            int token = wv * 128 + mt * 32 + row;
            float cvv = __uint_as_float(((uint32_t)Kf[token * 16 + ccol]) << 16);
            float oval = acc[mt][i] * __builtin_amdgcn_rcpf(dv) + breg + cvv;
            if (col < HD) {
                int l = ((token >> 4) << 10) + lbase + (((token >> 2) & 3) << 5) + (token & 3);
                out[((size_t)b * LTOT + l) * DIMC + cbase + col] = oval;
            }
        }
    }
}

extern "C" void kernel_launch(void* const* d_in, const int* in_sizes, int n_in,
                              void* d_out, int out_size, void* d_ws, size_t ws_size,
                              hipStream_t stream) {
    const float* qkv  = (const float*)d_in[0];
    const float* wgt  = (const float*)d_in[1];
    const float* bias = (const float*)d_in[2];
    float* out = (float*)d_out;
    attn_lepe<<<dim3(1024), dim3(256), 0, stream>>>(qkv, wgt, bias, out);
}

// Round 6
// 192.281 us; speedup vs baseline: 1.0561x; 1.0110x over previous
//
#include <hip/hip_runtime.h>
#include <stdint.h>

#define DIMC  128
#define HEADS 8
#define HD    16
#define WIN   512
#define LTOT  32768
#define NB    2

typedef __bf16 bf16x8_t __attribute__((ext_vector_type(8)));
typedef float f32x16_t  __attribute__((ext_vector_type(16)));
typedef float f32x4_t   __attribute__((ext_vector_type(4)));
typedef unsigned int u32x2_t __attribute__((ext_vector_type(2)));
union U128 { uint4 u; bf16x8_t v; };

__device__ __forceinline__ uint32_t rne_pair(float lo, float hi) {
    uint32_t a = __float_as_uint(lo), b = __float_as_uint(hi);
    a = (a + 0x7fffu + ((a >> 16) & 1u)) >> 16;
    b = (b + 0x7fffu + ((b >> 16) & 1u)) >> 16;
    return a | (b << 16);
}
__device__ __forceinline__ unsigned short rne1(float x) {
    uint32_t a = __float_as_uint(x);
    return (unsigned short)((a + 0x7fffu + ((a >> 16) & 1u)) >> 16);
}
// (lo>>16) | (hi & 0xffff0000): single v_perm_b32, bit-identical RTZ pack.
__device__ __forceinline__ uint32_t trunc_pair(float lo, float hi) {
    return __builtin_amdgcn_perm(__float_as_uint(hi), __float_as_uint(lo), 0x07060302u);
}
__device__ __forceinline__ float fast_exp2(float x) {
#if __has_builtin(__builtin_amdgcn_exp2f)
    return __builtin_amdgcn_exp2f(x);
#else
    return exp2f(x);
#endif
}

// One block per (window, head), 4 waves x 128 q-rows (256 threads).
// SOFTWARE-PIPELINED main loop: S for iteration n+1 is issued (QK MFMA)
// right after the exps of iteration n consume S_cur, so the QK latency
// hides under pack/PV of n, and PV's matrix-pipe occupancy hides under the
// exp batch of n+1 (intra-wave MFMA||VALU overlap). Occupancy proven
// irrelevant (R2/R3/R5: 3,4,6 waves/SIMD identical) -> attack chain, not
// waves. 32x32x16 MFMA for S^T = K*Q^T and O = P*V; P transposed C->A
// in-register via v_permlane32_swap_b32. Softmax without max-subtraction,
// den via ones-row in Vt. LePE conv as per-channel im2col MFMA (16x16x32).
// LDS ~38KB -> 4 blocks/CU; head=blk>>7 mapping keeps partner-head blocks
// co-resident for L2 write-combining (WRITE_SIZE == output size).
__global__ void __launch_bounds__(256, 3) attn_lepe(
    const float* __restrict__ qkv,   // [3, 2, 32768, 128] fp32
    const float* __restrict__ wgt,   // [128, 1, 5, 5, 5]  fp32
    const float* __restrict__ bias,  // [128]              fp32
    float* __restrict__ out)         // [2, 32768, 128]    fp32
{
    // Kf: K A-fragments (16 chunks x 512 bf16). Reused as conv-out Cl[token][ch].
    __shared__ __align__(16) unsigned short Kf[16 * 512];      // 16384 B
    // Vt: channel-major V, rows 0..15 = channels, row 16 = ones (den). Padded 520.
    __shared__ __align__(16) unsigned short Vt[17 * 520];      // 17680 B
    __shared__ __align__(16) unsigned short Wb[125 * 16];      // 4000 B, [tap][ch]
    __shared__ __align__(16) unsigned short Zp[16];            // 32 B zeros (conv halo)

    const int blk  = blockIdx.x;
    const int head = blk >> 7;          // swizzle: 8 heads of a window adjacent
    const int wi   = blk & 127;
    const int b    = wi >> 6;
    const int rem  = wi & 63;
    const int lbase = ((rem >> 3) << 7) + ((rem & 7) << 2);
    const int t    = threadIdx.x;
    const int lane = t & 63;
    const int wv   = t >> 6;
    const int cbase = head * HD;

    const int col  = lane & 31;
    const int hsel = lane >> 5;

    const float* Qg = qkv + (size_t)b * LTOT * DIMC;
    const float* Kg = Qg + (size_t)NB * LTOT * DIMC;
    const float* Vg = Kg + (size_t)NB * LTOT * DIMC;

    // ---------- stage K (A-frag order) and V (channel-major) ----------
    for (int u = t; u < 1024; u += 256) {
        int tp = u >> 2, ch4 = u & 3;
        int p  = tp << 1;               // even token; p+1 is l+1 (same h,w)
        int hh = p >> 4, ww = (p >> 2) & 3, ss = p & 3;
        int l  = (hh << 10) + lbase + (ww << 5) + ss;
        size_t g = (size_t)l * DIMC + cbase + (ch4 << 2);
        float4 k0 = *(const float4*)&Kg[g];
        float4 k1 = *(const float4*)&Kg[g + DIMC];
        float4 v0 = *(const float4*)&Vg[g];
        float4 v1 = *(const float4*)&Vg[g + DIMC];
        // Kf: value(lane,j) = K[c*32 + (lane&31)][8*(lane>>5)+j]
        int c  = p >> 5;
        int fl = (p & 31) + ((ch4 >> 1) << 5);
        int jo = (ch4 & 1) << 2;
        *(uint2*)&Kf[c * 512 + fl * 8 + jo] =
            make_uint2(rne_pair(k0.x, k0.y), rne_pair(k0.z, k0.w));
        *(uint2*)&Kf[c * 512 + (fl + 1) * 8 + jo] =
            make_uint2(rne_pair(k1.x, k1.y), rne_pair(k1.z, k1.w));
        // Vt: pair write (tokens p, p+1) per channel
        float a0[4] = {v0.x, v0.y, v0.z, v0.w};
        float a1[4] = {v1.x, v1.y, v1.z, v1.w};
#pragma unroll
        for (int i = 0; i < 4; ++i)
            *(uint32_t*)&Vt[((ch4 << 2) + i) * 520 + p] = rne_pair(a0[i], a1[i]);
    }
    // ones row (den): 512 entries = 128 threads x 4 bf16
    if (t < 128) ((uint2*)&Vt[16 * 520])[t] = make_uint2(0x3F803F80u, 0x3F803F80u);
    if (t < 8)  ((uint32_t*)Zp)[t & 7] = 0u;
    for (int e = t; e < 125 * HD; e += 256) {
        int tap = e >> 4, d = e & 15;
        Wb[e] = rne1(wgt[(size_t)(cbase + d) * 125 + tap]);
    }

    // ---------- per-wave Q B-fragments (scale * log2(e) folded in) ----------
    const float QSC = 0.25f * 1.44269504088896340736f;
    bf16x8_t qf[4];
#pragma unroll
    for (int mt = 0; mt < 4; ++mt) {
        int qrow = wv * 128 + mt * 32 + col;
        int l = ((qrow >> 4) << 10) + lbase + (((qrow >> 2) & 3) << 5) + (qrow & 3);
        const float* qp = &Qg[(size_t)l * DIMC + cbase + hsel * 8];
        float4 a = *(const float4*)qp;
        float4 c4 = *(const float4*)(qp + 4);
        U128 u;
        u.u.x = rne_pair(a.x * QSC, a.y * QSC);
        u.u.y = rne_pair(a.z * QSC, a.w * QSC);
        u.u.z = rne_pair(c4.x * QSC, c4.y * QSC);
        u.u.w = rne_pair(c4.z * QSC, c4.w * QSC);
        qf[mt] = u.v;
    }
    float breg = (col < HD) ? bias[cbase + col] : 0.f;

    __syncthreads();

    // ---------- attention main loop (software-pipelined) ----------
    f32x16_t acc[4];
#pragma unroll
    for (int mt = 0; mt < 4; ++mt)
#pragma unroll
        for (int i = 0; i < 16; ++i) acc[mt][i] = 0.f;
    f32x16_t zv;
#pragma unroll
    for (int i = 0; i < 16; ++i) zv[i] = 0.f;

    const int vcol = (col <= 16) ? col : 16;
    const int voff = vcol * 520;

    // register double-buffer: LDS fragments for iteration c loaded at c-1.
    U128 kf, vf0, vf1, kfn, vf0n, vf1n;
    kf.u  = *(const uint4*)&Kf[lane * 8];
    vf0.u = *(const uint4*)&Vt[voff + hsel * 8];
    vf1.u = *(const uint4*)&Vt[voff + 16 + hsel * 8];

    // prologue: S for (c=0, mt=0)
    f32x16_t S = __builtin_amdgcn_mfma_f32_32x32x16_bf16(kf.v, qf[0], zv, 0, 0, 0);

    for (int c = 0; c < 16; ++c) {
        if (c < 15) {
            kfn.u  = *(const uint4*)&Kf[(c + 1) * 512 + lane * 8];
            vf0n.u = *(const uint4*)&Vt[voff + (c + 1) * 32 + hsel * 8];
            vf1n.u = *(const uint4*)&Vt[voff + (c + 1) * 32 + 16 + hsel * 8];
        }
#pragma unroll
        for (int mt = 0; mt < 4; ++mt) {
            // consume S NOW (it dies after the exps) ...
            float pe[16];
#pragma unroll
            for (int r = 0; r < 16; ++r) pe[r] = fast_exp2(S[r]);
            // ... then immediately issue the NEXT tile's QK MFMA so its
            // latency hides under pack/swap/PV of this iteration.
            if (mt < 3)
                S = __builtin_amdgcn_mfma_f32_32x32x16_bf16(kf.v, qf[mt + 1], zv, 0, 0, 0);
            else if (c < 15)
                S = __builtin_amdgcn_mfma_f32_32x32x16_bf16(kfn.v, qf[0], zv, 0, 0, 0);
            uint32_t pk[8];
#pragma unroll
            for (int r = 0; r < 8; ++r) pk[r] = trunc_pair(pe[2 * r], pe[2 * r + 1]);
            // C->A half-transpose: permlane32_swap(vdst=pk0, vsrc=pk2):
            //   r[0] = {pk0.lanes0-31, pk2.lanes0-31} = A0.x
            //   r[1] = {pk0.lanes32-63, pk2.lanes32-63} = A0.z
            U128 A0, A1;
#if __has_builtin(__builtin_amdgcn_permlane32_swap)
            u32x2_t rxz0 = __builtin_amdgcn_permlane32_swap(pk[0], pk[2], false, false);
            u32x2_t ryw0 = __builtin_amdgcn_permlane32_swap(pk[1], pk[3], false, false);
            u32x2_t rxz1 = __builtin_amdgcn_permlane32_swap(pk[4], pk[6], false, false);
            u32x2_t ryw1 = __builtin_amdgcn_permlane32_swap(pk[5], pk[7], false, false);
            A0.u = make_uint4(rxz0[0], ryw0[0], rxz0[1], ryw0[1]);
            A1.u = make_uint4(rxz1[0], ryw1[0], rxz1[1], ryw1[1]);
#else
            uint32_t xa = __shfl_xor(hsel ? pk[0] : pk[2], 32);
            uint32_t xb = __shfl_xor(hsel ? pk[1] : pk[3], 32);
            uint32_t xc = __shfl_xor(hsel ? pk[4] : pk[6], 32);
            uint32_t xd = __shfl_xor(hsel ? pk[5] : pk[7], 32);
            A0.u = hsel ? make_uint4(xa, xb, pk[2], pk[3])
                        : make_uint4(pk[0], pk[1], xa, xb);
            A1.u = hsel ? make_uint4(xc, xd, pk[6], pk[7])
                        : make_uint4(pk[4], pk[5], xc, xd);
#endif
            __builtin_amdgcn_s_setprio(1);
            acc[mt] = __builtin_amdgcn_mfma_f32_32x32x16_bf16(A0.v, vf0.v, acc[mt], 0, 0, 0);
            acc[mt] = __builtin_amdgcn_mfma_f32_32x32x16_bf16(A1.v, vf1.v, acc[mt], 0, 0, 0);
            __builtin_amdgcn_s_setprio(0);
        }
        kf = kfn; vf0 = vf0n; vf1 = vf1n;
    }

    __syncthreads();   // all waves done with Kf -> reuse as Cl

    // ---------- LePE conv as per-channel im2col MFMA ----------
    // C[h][sigma] = sum_{dh,tau} V[h+dh-2][tau][ch] * M[(dh,tau)][sigma]
    {
        const int sg  = lane & 15;       // sigma = w*4+s (output ws)
        const int khi = lane >> 4;       // k-group
        const int tb  = (khi & 1) * 8;   // tau base for this lane's j-run
#pragma unroll
        for (int cc = 0; cc < 4; ++cc) {
            const int cch = wv * 4 + cc;
            // B-frags: Toeplitz weights, built from Wb
            U128 Bf[3];
#pragma unroll
            for (int kc = 0; kc < 3; ++kc) {
                int dh = 2 * kc + (khi >> 1);
                uint32_t pr[4];
#pragma unroll
                for (int jp = 0; jp < 4; ++jp) {
                    uint32_t w01 = 0;
#pragma unroll
                    for (int e = 0; e < 2; ++e) {
                        int tau = tb + jp * 2 + e;
                        int dw = (tau >> 2) - (sg >> 2);
                        int ds = (tau & 3) - (sg & 3);
                        bool valid = (dh < 5) && (dw >= -2) && (dw <= 2) && (ds >= -2) && (ds <= 2);
                        int tap = dh * 25 + (dw + 2) * 5 + (ds + 2);
                        uint32_t wv16 = valid ? (uint32_t)Wb[(valid ? tap : 0) * 16 + cch] : 0u;
                        w01 |= wv16 << (16 * e);
                    }
                    pr[jp] = w01;
                }
                Bf[kc].u = make_uint4(pr[0], pr[1], pr[2], pr[3]);
            }
#pragma unroll
            for (int mt2 = 0; mt2 < 2; ++mt2) {
                f32x4_t cacc = {0.f, 0.f, 0.f, 0.f};
#pragma unroll
                for (int kc = 0; kc < 3; ++kc) {
                    int dh = 2 * kc + (khi >> 1);
                    int h_in = mt2 * 16 + (lane & 15) + dh - 2;
                    const unsigned short* ap =
                        (h_in >= 0 && h_in < 32 && dh < 5)
                            ? &Vt[cch * 520 + h_in * 16 + tb]
                            : Zp;
                    U128 af; af.u = *(const uint4*)ap;
                    cacc = __builtin_amdgcn_mfma_f32_16x16x32_bf16(af.v, Bf[kc].v, cacc, 0, 0, 0);
                }
                // C-layout 16x16: col=lane&15 (=sigma), row=(lane>>4)*4+reg
#pragma unroll
                for (int r = 0; r < 4; ++r) {
                    int h = mt2 * 16 + khi * 4 + r;
                    Kf[(h * 16 + sg) * 16 + cch] = rne1(cacc[r]);
                }
            }
        }
    }

    __syncthreads();

    // ---------- epilogue: O/den + bias + conv ----------
    const int ccol = col & 15;
#pragma unroll
    for (int mt = 0; mt < 4; ++mt) {
#pragma unroll
        for (int i = 0; i < 16; ++i) {
            float dv = __shfl(acc[mt][i], 16 | (lane & 32), 64);  // den col 16
            int row = (i & 3) + ((i >> 2) << 3) + (hsel << 2);
            int token = wv * 128 + mt * 32 + row;
            float cvv = __uint_as_float(((uint32_t)Kf[token * 16 + ccol]) << 16);
            float oval = acc[mt][i] * __builtin_amdgcn_rcpf(dv) + breg + cvv;
            if (col < HD) {
                int l = ((token >> 4) << 10) + lbase + (((token >> 2) & 3) << 5) + (token & 3);
                out[((size_t)b * LTOT + l) * DIMC + cbase + col] = oval;
            }
        }
    }
}

extern "C" void kernel_launch(void* const* d_in, const int* in_sizes, int n_in,
                              void* d_out, int out_size, void* d_ws, size_t ws_size,
                              hipStream_t stream) {
    const float* qkv  = (const float*)d_in[0];
    const float* wgt  = (const float*)d_in[1];
    const float* bias = (const float*)d_in[2];
    float* out = (float*)d_out;
    attn_lepe<<<dim3(1024), dim3(256), 0, stream>>>(qkv, wgt, bias, out);
}

// Round 8
// 192.247 us; speedup vs baseline: 1.0563x; 1.0002x over previous
//
#include <hip/hip_runtime.h>
#include <stdint.h>

#define DIMC  128
#define HEADS 8
#define HD    16
#define WIN   512
#define LTOT  32768
#define NB    2

typedef __bf16 bf16x8_t __attribute__((ext_vector_type(8)));
typedef float f32x16_t  __attribute__((ext_vector_type(16)));
typedef float f32x4_t   __attribute__((ext_vector_type(4)));
typedef unsigned int u32x2_t __attribute__((ext_vector_type(2)));
union U128 { uint4 u; bf16x8_t v; };

__device__ __forceinline__ uint32_t rne_pair(float lo, float hi) {
    uint32_t a = __float_as_uint(lo), b = __float_as_uint(hi);
    a = (a + 0x7fffu + ((a >> 16) & 1u)) >> 16;
    b = (b + 0x7fffu + ((b >> 16) & 1u)) >> 16;
    return a | (b << 16);
}
__device__ __forceinline__ unsigned short rne1(float x) {
    uint32_t a = __float_as_uint(x);
    return (unsigned short)((a + 0x7fffu + ((a >> 16) & 1u)) >> 16);
}
// (lo>>16) | (hi & 0xffff0000): single v_perm_b32, bit-identical RTZ pack.
__device__ __forceinline__ uint32_t trunc_pair(float lo, float hi) {
    return __builtin_amdgcn_perm(__float_as_uint(hi), __float_as_uint(lo), 0x07060302u);
}
__device__ __forceinline__ float fast_exp2(float x) {
#if __has_builtin(__builtin_amdgcn_exp2f)
    return __builtin_amdgcn_exp2f(x);
#else
    return exp2f(x);
#endif
}

// One block per (window, head), 4 waves x 128 q-rows (256 threads).
// launch_bounds(256,2): VGPR_Count froze at 76 across three scheduling
// attempts (R3/R5/R6) -> the compiler was register-starved at the (256,3)
// budget and re-serialized the softmax chain (and bounced S through AGPRs,
// costing hidden v_accvgpr_read VALU). 2 waves/EU doubles the budget so
// pe/pk/A and two S-tiles stay live in arch VGPRs. Occupancy proven
// irrelevant (R2/R3/R5: 8-24 waves/CU identical). Residency at 2 blocks/CU
// keeps head-pair (blk, blk+128) L2 write-combining (same XCD).
// Inner body: next-tile QK issued FIRST (longest-latency head), softmax
// split in two independent half-chains (8 exps -> 4 packs -> 2 permlane
// swaps -> PV half), second half overlaps PV_A0's pipe occupancy.
// 32x32x16 MFMA for S^T = K*Q^T and O = P*V; P transposed C->A in-register
// via v_permlane32_swap_b32. Softmax without max-subtraction, den via
// ones-row in Vt. LePE conv as per-channel im2col MFMA (16x16x32).
__global__ void __launch_bounds__(256, 2) attn_lepe(
    const float* __restrict__ qkv,   // [3, 2, 32768, 128] fp32
    const float* __restrict__ wgt,   // [128, 1, 5, 5, 5]  fp32
    const float* __restrict__ bias,  // [128]              fp32
    float* __restrict__ out)         // [2, 32768, 128]    fp32
{
    // Kf: K A-fragments (16 chunks x 512 bf16). Reused as conv-out Cl[token][ch].
    __shared__ __align__(16) unsigned short Kf[16 * 512];      // 16384 B
    // Vt: channel-major V, rows 0..15 = channels, row 16 = ones (den). Padded 520.
    __shared__ __align__(16) unsigned short Vt[17 * 520];      // 17680 B
    __shared__ __align__(16) unsigned short Wb[125 * 16];      // 4000 B, [tap][ch]
    __shared__ __align__(16) unsigned short Zp[16];            // 32 B zeros (conv halo)

    const int blk  = blockIdx.x;
    const int head = blk >> 7;          // swizzle: 8 heads of a window adjacent
    const int wi   = blk & 127;
    const int b    = wi >> 6;
    const int rem  = wi & 63;
    const int lbase = ((rem >> 3) << 7) + ((rem & 7) << 2);
    const int t    = threadIdx.x;
    const int lane = t & 63;
    const int wv   = t >> 6;
    const int cbase = head * HD;

    const int col  = lane & 31;
    const int hsel = lane >> 5;

    const float* Qg = qkv + (size_t)b * LTOT * DIMC;
    const float* Kg = Qg + (size_t)NB * LTOT * DIMC;
    const float* Vg = Kg + (size_t)NB * LTOT * DIMC;

    // ---------- stage K (A-frag order) and V (channel-major) ----------
    for (int u = t; u < 1024; u += 256) {
        int tp = u >> 2, ch4 = u & 3;
        int p  = tp << 1;               // even token; p+1 is l+1 (same h,w)
        int hh = p >> 4, ww = (p >> 2) & 3, ss = p & 3;
        int l  = (hh << 10) + lbase + (ww << 5) + ss;
        size_t g = (size_t)l * DIMC + cbase + (ch4 << 2);
        float4 k0 = *(const float4*)&Kg[g];
        float4 k1 = *(const float4*)&Kg[g + DIMC];
        float4 v0 = *(const float4*)&Vg[g];
        float4 v1 = *(const float4*)&Vg[g + DIMC];
        // Kf: value(lane,j) = K[c*32 + (lane&31)][8*(lane>>5)+j]
        int c  = p >> 5;
        int fl = (p & 31) + ((ch4 >> 1) << 5);
        int jo = (ch4 & 1) << 2;
        *(uint2*)&Kf[c * 512 + fl * 8 + jo] =
            make_uint2(rne_pair(k0.x, k0.y), rne_pair(k0.z, k0.w));
        *(uint2*)&Kf[c * 512 + (fl + 1) * 8 + jo] =
            make_uint2(rne_pair(k1.x, k1.y), rne_pair(k1.z, k1.w));
        // Vt: pair write (tokens p, p+1) per channel
        float a0[4] = {v0.x, v0.y, v0.z, v0.w};
        float a1[4] = {v1.x, v1.y, v1.z, v1.w};
#pragma unroll
        for (int i = 0; i < 4; ++i)
            *(uint32_t*)&Vt[((ch4 << 2) + i) * 520 + p] = rne_pair(a0[i], a1[i]);
    }
    // ones row (den): 512 entries = 128 threads x 4 bf16
    if (t < 128) ((uint2*)&Vt[16 * 520])[t] = make_uint2(0x3F803F80u, 0x3F803F80u);
    if (t < 8)  ((uint32_t*)Zp)[t & 7] = 0u;
    for (int e = t; e < 125 * HD; e += 256) {
        int tap = e >> 4, d = e & 15;
        Wb[e] = rne1(wgt[(size_t)(cbase + d) * 125 + tap]);
    }

    // ---------- per-wave Q B-fragments (scale * log2(e) folded in) ----------
    const float QSC = 0.25f * 1.44269504088896340736f;
    bf16x8_t qf[4];
#pragma unroll
    for (int mt = 0; mt < 4; ++mt) {
        int qrow = wv * 128 + mt * 32 + col;
        int l = ((qrow >> 4) << 10) + lbase + (((qrow >> 2) & 3) << 5) + (qrow & 3);
        const float* qp = &Qg[(size_t)l * DIMC + cbase + hsel * 8];
        float4 a = *(const float4*)qp;
        float4 c4 = *(const float4*)(qp + 4);
        U128 u;
        u.u.x = rne_pair(a.x * QSC, a.y * QSC);
        u.u.y = rne_pair(a.z * QSC, a.w * QSC);
        u.u.z = rne_pair(c4.x * QSC, c4.y * QSC);
        u.u.w = rne_pair(c4.z * QSC, c4.w * QSC);
        qf[mt] = u.v;
    }
    float breg = (col < HD) ? bias[cbase + col] : 0.f;

    __syncthreads();

    // ---------- attention main loop (software-pipelined) ----------
    f32x16_t acc[4];
#pragma unroll
    for (int mt = 0; mt < 4; ++mt)
#pragma unroll
        for (int i = 0; i < 16; ++i) acc[mt][i] = 0.f;
    f32x16_t zv;
#pragma unroll
    for (int i = 0; i < 16; ++i) zv[i] = 0.f;

    const int vcol = (col <= 16) ? col : 16;
    const int voff = vcol * 520;

    // register double-buffer: LDS fragments for iteration c loaded at c-1.
    U128 kf, vf0, vf1, kfn, vf0n, vf1n;
    kf.u  = *(const uint4*)&Kf[lane * 8];
    vf0.u = *(const uint4*)&Vt[voff + hsel * 8];
    vf1.u = *(const uint4*)&Vt[voff + 16 + hsel * 8];

    // prologue: S for (c=0, mt=0)
    f32x16_t S = __builtin_amdgcn_mfma_f32_32x32x16_bf16(kf.v, qf[0], zv, 0, 0, 0);

    for (int c = 0; c < 16; ++c) {
        if (c < 15) {
            kfn.u  = *(const uint4*)&Kf[(c + 1) * 512 + lane * 8];
            vf0n.u = *(const uint4*)&Vt[voff + (c + 1) * 32 + hsel * 8];
            vf1n.u = *(const uint4*)&Vt[voff + (c + 1) * 32 + 16 + hsel * 8];
        }
#pragma unroll
        for (int mt = 0; mt < 4; ++mt) {
            // Issue the NEXT tile's QK FIRST: its full MFMA latency hides
            // under this tile's softmax + PV. (S is still read below; the
            // compiler renames. Dead-copy in the final iteration folds.)
            f32x16_t Sn = S;
            if (mt < 3)
                Sn = __builtin_amdgcn_mfma_f32_32x32x16_bf16(kf.v, qf[mt + 1], zv, 0, 0, 0);
            else if (c < 15)
                Sn = __builtin_amdgcn_mfma_f32_32x32x16_bf16(kfn.v, qf[0], zv, 0, 0, 0);

            // ---- half-chain 0: exps 0..7 -> pk0..3 -> A0 -> PV_A0 ----
            float pe0[8];
#pragma unroll
            for (int r = 0; r < 8; ++r) pe0[r] = fast_exp2(S[r]);
            uint32_t pk[8];
#pragma unroll
            for (int r = 0; r < 4; ++r) pk[r] = trunc_pair(pe0[2 * r], pe0[2 * r + 1]);
            // C->A half-transpose: permlane32_swap(vdst=pk0, vsrc=pk2):
            //   r[0] = {pk0.lanes0-31, pk2.lanes0-31} = A0.x
            //   r[1] = {pk0.lanes32-63, pk2.lanes32-63} = A0.z
            U128 A0;
#if __has_builtin(__builtin_amdgcn_permlane32_swap)
            u32x2_t rxz0 = __builtin_amdgcn_permlane32_swap(pk[0], pk[2], false, false);
            u32x2_t ryw0 = __builtin_amdgcn_permlane32_swap(pk[1], pk[3], false, false);
            A0.u = make_uint4(rxz0[0], ryw0[0], rxz0[1], ryw0[1]);
#else
            uint32_t xa = __shfl_xor(hsel ? pk[0] : pk[2], 32);
            uint32_t xb = __shfl_xor(hsel ? pk[1] : pk[3], 32);
            A0.u = hsel ? make_uint4(xa, xb, pk[2], pk[3])
                        : make_uint4(pk[0], pk[1], xa, xb);
#endif
            __builtin_amdgcn_s_setprio(1);
            acc[mt] = __builtin_amdgcn_mfma_f32_32x32x16_bf16(A0.v, vf0.v, acc[mt], 0, 0, 0);
            __builtin_amdgcn_s_setprio(0);

            // ---- half-chain 1: exps 8..15 -> pk4..7 -> A1 -> PV_A1 ----
            // (independent of half-chain 0; overlaps PV_A0's pipe occupancy)
            float pe1[8];
#pragma unroll
            for (int r = 0; r < 8; ++r) pe1[r] = fast_exp2(S[8 + r]);
#pragma unroll
            for (int r = 0; r < 4; ++r) pk[4 + r] = trunc_pair(pe1[2 * r], pe1[2 * r + 1]);
            U128 A1;
#if __has_builtin(__builtin_amdgcn_permlane32_swap)
            u32x2_t rxz1 = __builtin_amdgcn_permlane32_swap(pk[4], pk[6], false, false);
            u32x2_t ryw1 = __builtin_amdgcn_permlane32_swap(pk[5], pk[7], false, false);
            A1.u = make_uint4(rxz1[0], ryw1[0], rxz1[1], ryw1[1]);
#else
            uint32_t xc = __shfl_xor(hsel ? pk[4] : pk[6], 32);
            uint32_t xd = __shfl_xor(hsel ? pk[5] : pk[7], 32);
            A1.u = hsel ? make_uint4(xc, xd, pk[6], pk[7])
                        : make_uint4(pk[4], pk[5], xc, xd);
#endif
            __builtin_amdgcn_s_setprio(1);
            acc[mt] = __builtin_amdgcn_mfma_f32_32x32x16_bf16(A1.v, vf1.v, acc[mt], 0, 0, 0);
            __builtin_amdgcn_s_setprio(0);

            S = Sn;
        }
        kf = kfn; vf0 = vf0n; vf1 = vf1n;
    }

    __syncthreads();   // all waves done with Kf -> reuse as Cl

    // ---------- LePE conv as per-channel im2col MFMA ----------
    // C[h][sigma] = sum_{dh,tau} V[h+dh-2][tau][ch] * M[(dh,tau)][sigma]
    {
        const int sg  = lane & 15;       // sigma = w*4+s (output ws)
        const int khi = lane >> 4;       // k-group
        const int tb  = (khi & 1) * 8;   // tau base for this lane's j-run
#pragma unroll
        for (int cc = 0; cc < 4; ++cc) {
            const int cch = wv * 4 + cc;
            // B-frags: Toeplitz weights, built from Wb
            U128 Bf[3];
#pragma unroll
            for (int kc = 0; kc < 3; ++kc) {
                int dh = 2 * kc + (khi >> 1);
                uint32_t pr[4];
#pragma unroll
                for (int jp = 0; jp < 4; ++jp) {
                    uint32_t w01 = 0;
#pragma unroll
                    for (int e = 0; e < 2; ++e) {
                        int tau = tb + jp * 2 + e;
                        int dw = (tau >> 2) - (sg >> 2);
                        int ds = (tau & 3) - (sg & 3);
                        bool valid = (dh < 5) && (dw >= -2) && (dw <= 2) && (ds >= -2) && (ds <= 2);
                        int tap = dh * 25 + (dw + 2) * 5 + (ds + 2);
                        uint32_t wv16 = valid ? (uint32_t)Wb[(valid ? tap : 0) * 16 + cch] : 0u;
                        w01 |= wv16 << (16 * e);
                    }
                    pr[jp] = w01;
                }
                Bf[kc].u = make_uint4(pr[0], pr[1], pr[2], pr[3]);
            }
#pragma unroll
            for (int mt2 = 0; mt2 < 2; ++mt2) {
                f32x4_t cacc = {0.f, 0.f, 0.f, 0.f};
#pragma unroll
                for (int kc = 0; kc < 3; ++kc) {
                    int dh = 2 * kc + (khi >> 1);
                    int h_in = mt2 * 16 + (lane & 15) + dh - 2;
                    const unsigned short* ap =
                        (h_in >= 0 && h_in < 32 && dh < 5)
                            ? &Vt[cch * 520 + h_in * 16 + tb]
                            : Zp;
                    U128 af; af.u = *(const uint4*)ap;
                    cacc = __builtin_amdgcn_mfma_f32_16x16x32_bf16(af.v, Bf[kc].v, cacc, 0, 0, 0);
                }
                // C-layout 16x16: col=lane&15 (=sigma), row=(lane>>4)*4+reg
#pragma unroll
                for (int r = 0; r < 4; ++r) {
                    int h = mt2 * 16 + khi * 4 + r;
                    Kf[(h * 16 + sg) * 16 + cch] = rne1(cacc[r]);
                }
            }
        }
    }

    __syncthreads();

    // ---------- epilogue: O/den + bias + conv ----------
    const int ccol = col & 15;
#pragma unroll
    for (int mt = 0; mt < 4; ++mt) {
#pragma unroll
        for (int i = 0; i < 16; ++i) {
            float dv = __shfl(acc[mt][i], 16 | (lane & 32), 64);  // den col 16
            int row = (i & 3) + ((i >> 2) << 3) + (hsel << 2);
            int token = wv * 128 + mt * 32 + row;
            float cvv = __uint_as_float(((uint32_t)Kf[token * 16 + ccol]) << 16);
            float oval = acc[mt][i] * __builtin_amdgcn_rcpf(dv) + breg + cvv;
            if (col < HD) {
                int l = ((token >> 4) << 10) + lbase + (((token >> 2) & 3) << 5) + (token & 3);
                out[((size_t)b * LTOT + l) * DIMC + cbase + col] = oval;
            }
        }
    }
}

extern "C" void kernel_launch(void* const* d_in, const int* in_sizes, int n_in,
                              void* d_out, int out_size, void* d_ws, size_t ws_size,
                              hipStream_t stream) {
    const float* qkv  = (const float*)d_in[0];
    const float* wgt  = (const float*)d_in[1];
    const float* bias = (const float*)d_in[2];
    float* out = (float*)d_out;
    attn_lepe<<<dim3(1024), dim3(256), 0, stream>>>(qkv, wgt, bias, out);
}